// Round 5
// baseline (1691.162 us; speedup 1.0000x reference)
//
#include <hip/hip_runtime.h>
#include <hip/hip_bf16.h>

#define N_NODES 100000
#define N_EDGES 1600000
#define N_EL    200000
// Round 20: single persistent mega-kernel (1024 blocks = 4/CU, co-resident by
// construction: 32KB LDS, launch_bounds(256,4) => VGPR<=128) with hand-rolled
// monotonic grid barriers (agent-scope atomics). Eliminates ~9 inter-dispatch
// gaps (~10us each, inferred from round-2/3 accounting: sum(kernels) ~310us vs
// 437 measured). CSR build = atomic rank (counting sort lost 45us, round 4).
// gemm3 now writes dense 64-wide z (halves gather64 line footprint). CPAD=1.
// Dispatches: 2 (memset + mega).

#define NB2 ((N_NODES + 511) / 512)        // 196 scan chunks
#define GT_GEMM ((N_NODES + 63) / 64)      // 1563 gemm tiles
#define GRIDN 1024

typedef unsigned int uint32;
typedef unsigned short ushort16;
typedef __attribute__((ext_vector_type(8))) short short8;   // 8 bf16
typedef __attribute__((ext_vector_type(4))) float f32x4;

static __device__ __forceinline__ ushort16 f2bf(float f) {
    uint32 u = __float_as_uint(f);
    u += 0x7fffu + ((u >> 16) & 1u);      // RNE
    return (ushort16)(u >> 16);
}
static __device__ __forceinline__ float bf_lo(uint32 p) { return __uint_as_float(p << 16); }
static __device__ __forceinline__ float bf_hi(uint32 p) { return __uint_as_float(p & 0xffff0000u); }
static __device__ __forceinline__ uint32 pack2(float lo, float hi) {
    return (uint32)f2bf(lo) | ((uint32)f2bf(hi) << 16);
}

// ---- grid barrier: monotonic arrival counter, agent scope (zeroed by host) ----
static __device__ __forceinline__ void gsync(int* cbar, int phase, int tid) {
    __syncthreads();
    if (tid == 0) {
        __hip_atomic_fetch_add(cbar, 1, __ATOMIC_ACQ_REL, __HIP_MEMORY_SCOPE_AGENT);
        while (__hip_atomic_load(cbar, __ATOMIC_ACQUIRE, __HIP_MEMORY_SCOPE_AGENT)
               < phase * GRIDN)
            __builtin_amdgcn_s_sleep(8);
    }
    __syncthreads();
}

// ---------------- A-fragment loaders ----------------
static __device__ __forceinline__ short8 load_afrag(const float* arow, int off) {
    float4 a0 = *(const float4*)(arow + off);
    float4 a1 = *(const float4*)(arow + off + 4);
    short8 af;
    af[0] = (short)f2bf(a0.x); af[1] = (short)f2bf(a0.y);
    af[2] = (short)f2bf(a0.z); af[3] = (short)f2bf(a0.w);
    af[4] = (short)f2bf(a1.x); af[5] = (short)f2bf(a1.y);
    af[6] = (short)f2bf(a1.z); af[7] = (short)f2bf(a1.w);
    return af;
}
static __device__ __forceinline__ short8 load_afrag(const ushort16* arow, int off) {
    return *(const short8*)(arow + off);   // 16B aligned
}

// ---- MFMA GEMM tile: C[n,0:D] = bf16([dinv[n]] * (A[n,:128] @ W[128,D])) ------
// Top __syncthreads protects LDS reuse across sequential tasks in one block.
template <int D, typename AT, bool SCALE, int OS>
static __device__ __forceinline__ void gemm_body(int bid, const AT* __restrict__ A,
        const float* __restrict__ W, const float* __restrict__ dinv,
        ushort16* __restrict__ C, short* sB) {
    constexpr int NT = D / 16;                 // 8 (D=128) or 4 (D=64)
    constexpr int LNT = (NT == 8) ? 3 : 2;
    int tid = threadIdx.x;
    __syncthreads();

    constexpr int COMBOS = 4 * 4 * NT * 16;    // 2048 / 1024
    for (int cc = tid; cc < COMBOS; cc += 256) {
        int nn = cc & 15;
        int nt = (cc >> 4) & (NT - 1);
        int q  = (cc >> (4 + LNT)) & 3;
        int kt = cc >> (6 + LNT);
        short8 pk;
#pragma unroll
        for (int j = 0; j < 8; ++j)
            pk[j] = (short)f2bf(W[(kt * 32 + q * 8 + j) * D + nt * 16 + nn]);
        *(short8*)&sB[(((kt * NT + nt) * 64) + q * 16 + nn) * 8] = pk;
    }
    __syncthreads();

    int w = tid >> 6;
    int l = tid & 63;
    int q = l >> 4;
    int nn15 = l & 15;
    int m0 = bid * 64 + w * 16;

    f32x4 acc[NT];
#pragma unroll
    for (int i = 0; i < NT; ++i) acc[i] = (f32x4){0.f, 0.f, 0.f, 0.f};

    int m = m0 + nn15;
    m = min(m, N_NODES - 1);                    // tail clamp (loads only)
    const AT* arow = A + (size_t)m * 128;

#pragma unroll
    for (int kt = 0; kt < 4; ++kt) {
        short8 af = load_afrag(arow, kt * 32 + q * 8);
#pragma unroll
        for (int nt = 0; nt < NT; ++nt) {
            short8 bf = *(const short8*)&sB[((kt * NT + nt) * 64 + l) * 8];
            acc[nt] = __builtin_amdgcn_mfma_f32_16x16x32_bf16(af, bf, acc[nt], 0, 0, 0);
        }
    }

    float4 dvv;
    if constexpr (SCALE) dvv = *(const float4*)(dinv + m0 + 4 * q);
    const float* dvp = (const float*)&dvv;
#pragma unroll
    for (int nt = 0; nt < NT; ++nt) {
#pragma unroll
        for (int rr = 0; rr < 4; ++rr) {
            int node = m0 + q * 4 + rr;
            if (node < N_NODES) {
                float val = acc[nt][rr];
                if constexpr (SCALE) val *= dvp[rr];
                C[(size_t)node * OS + nt * 16 + nn15] = f2bf(val);
            }
        }
    }
}

// ---------------- gather, D=128: 8B/lane, 2 rows per load instruction -----------
template <bool RELU>
static __device__ __forceinline__ void gather128_phase(const int* __restrict__ rowptr,
        const int* __restrict__ col, const float* __restrict__ dinv,
        const uint32* __restrict__ t, const float* __restrict__ b,
        uint32* __restrict__ outbuf, int bid, int tid, void* smem) {
    int (*sc)[64] = (int(*)[64])smem;
    int w = tid >> 6;
    int lane = tid & 63;
    int h = lane >> 5;
    int k = lane & 31;
    for (int wid = bid * 4 + w; wid < N_NODES; wid += GRIDN * 4) {
        int beg = rowptr[wid], end = rowptr[wid + 1];
        float a0 = 0.f, a1 = 0.f, a2 = 0.f, a3 = 0.f;
        if (h == 0) {
            uint2 p = ((const uint2*)(t + (size_t)wid * 64))[k];
            a0 = bf_lo(p.x); a1 = bf_hi(p.x); a2 = bf_lo(p.y); a3 = bf_hi(p.y);
        }
        for (int base = beg; base < end; base += 64) {
            int cnt = min(end - base, 64);
            int c = N_NODES;
            if (lane < cnt) c = col[base + lane];
            sc[w][lane] = c;             // same-wave LDS, no barrier needed
            int nb8 = (cnt + 7) >> 3;
            for (int j8 = 0; j8 < nb8; ++j8) {
                int j = j8 << 3;
                int r0 = sc[w][j + 0 + h];
                int r1 = sc[w][j + 2 + h];
                int r2 = sc[w][j + 4 + h];
                int r3 = sc[w][j + 6 + h];
                uint2 v0 = ((const uint2*)(t + (size_t)r0 * 64))[k];
                uint2 v1 = ((const uint2*)(t + (size_t)r1 * 64))[k];
                uint2 v2 = ((const uint2*)(t + (size_t)r2 * 64))[k];
                uint2 v3 = ((const uint2*)(t + (size_t)r3 * 64))[k];
                a0 += (bf_lo(v0.x) + bf_lo(v1.x)) + (bf_lo(v2.x) + bf_lo(v3.x));
                a1 += (bf_hi(v0.x) + bf_hi(v1.x)) + (bf_hi(v2.x) + bf_hi(v3.x));
                a2 += (bf_lo(v0.y) + bf_lo(v1.y)) + (bf_lo(v2.y) + bf_lo(v3.y));
                a3 += (bf_hi(v0.y) + bf_hi(v1.y)) + (bf_hi(v2.y) + bf_hi(v3.y));
            }
        }
        a0 += __shfl_xor(a0, 32);
        a1 += __shfl_xor(a1, 32);
        a2 += __shfl_xor(a2, 32);
        a3 += __shfl_xor(a3, 32);
        if (h == 0) {
            float di = dinv[wid];
            float4 bb = ((const float4*)b)[k];
            float o0 = fmaf(di, a0, bb.x);
            float o1 = fmaf(di, a1, bb.y);
            float o2 = fmaf(di, a2, bb.z);
            float o3 = fmaf(di, a3, bb.w);
            if (RELU) {
                o0 = fmaxf(o0, 0.f); o1 = fmaxf(o1, 0.f);
                o2 = fmaxf(o2, 0.f); o3 = fmaxf(o3, 0.f);
            }
            unsigned long long pv = (unsigned long long)pack2(o0, o1)
                                  | ((unsigned long long)pack2(o2, o3) << 32);
            *((unsigned long long*)(outbuf + (size_t)wid * 64) + k) = pv;
        }
    }
}

// ---------------- gather, D=64: dense z (stride 32 uint32), 4 rows/instr --------
static __device__ __forceinline__ void gather64_phase(const int* __restrict__ rowptr,
        const int* __restrict__ col, const float* __restrict__ dinv,
        const uint32* __restrict__ z, const float* __restrict__ b,
        uint32* __restrict__ outbuf, int bid, int tid, void* smem) {
    int (*sc)[64] = (int(*)[64])smem;
    int w = tid >> 6;
    int lane = tid & 63;
    int h = lane >> 4;              // 0..3
    int k = lane & 15;              // uint2 index (dims 4k..4k+3 of 64)
    for (int wid = bid * 4 + w; wid < N_NODES; wid += GRIDN * 4) {
        int beg = rowptr[wid], end = rowptr[wid + 1];
        float a0 = 0.f, a1 = 0.f, a2 = 0.f, a3 = 0.f;
        if (h == 0) {
            uint2 p = ((const uint2*)(z + (size_t)wid * 32))[k];
            a0 = bf_lo(p.x); a1 = bf_hi(p.x); a2 = bf_lo(p.y); a3 = bf_hi(p.y);
        }
        for (int base = beg; base < end; base += 64) {
            int cnt = min(end - base, 64);
            int c = N_NODES;
            if (lane < cnt) c = col[base + lane];
            sc[w][lane] = c;
            int nb8 = (cnt + 7) >> 3;
            for (int j8 = 0; j8 < nb8; ++j8) {
                int j = j8 << 3;
                int r0 = sc[w][j + h];
                int r1 = sc[w][j + 4 + h];
                uint2 v0 = ((const uint2*)(z + (size_t)r0 * 32))[k];
                uint2 v1 = ((const uint2*)(z + (size_t)r1 * 32))[k];
                a0 += bf_lo(v0.x) + bf_lo(v1.x);
                a1 += bf_hi(v0.x) + bf_hi(v1.x);
                a2 += bf_lo(v0.y) + bf_lo(v1.y);
                a3 += bf_hi(v0.y) + bf_hi(v1.y);
            }
        }
        a0 += __shfl_xor(a0, 16); a0 += __shfl_xor(a0, 32);
        a1 += __shfl_xor(a1, 16); a1 += __shfl_xor(a1, 32);
        a2 += __shfl_xor(a2, 16); a2 += __shfl_xor(a2, 32);
        a3 += __shfl_xor(a3, 16); a3 += __shfl_xor(a3, 32);
        if (h == 0) {
            float di = dinv[wid];
            float4 bb = ((const float4*)b)[k];
            float o0 = fmaf(di, a0, bb.x);
            float o1 = fmaf(di, a1, bb.y);
            float o2 = fmaf(di, a2, bb.z);
            float o3 = fmaf(di, a3, bb.w);
            unsigned long long pv = (unsigned long long)pack2(o0, o1)
                                  | ((unsigned long long)pack2(o2, o3) << 32);
            *((unsigned long long*)(outbuf + (size_t)wid * 32) + k) = pv;
        }
    }
}

// ---------------- the mega-kernel ----------------
__global__ __launch_bounds__(256, 4) void k_mega(
    const float* __restrict__ x, const int* __restrict__ ei,
    const int* __restrict__ eli,
    const float* __restrict__ W1, const float* __restrict__ b1,
    const float* __restrict__ W2, const float* __restrict__ b2,
    const float* __restrict__ W3, const float* __restrict__ b3,
    float* __restrict__ out,
    float* __restrict__ dinv, int* __restrict__ lrp, int* __restrict__ rowptr,
    int* __restrict__ bsum, int* __restrict__ cpad, int* __restrict__ cbar,
    int* __restrict__ col, int* __restrict__ r,
    ushort16* __restrict__ t, ushort16* __restrict__ aggb)
{
    __shared__ __align__(16) char smem[32768];
    const int tid = threadIdx.x;
    const int bid = blockIdx.x;
    const int* srcA = ei;
    const int* dstA = ei + N_EDGES;
    uint32* t32 = (uint32*)t;

    // ---- P1: gemm1 tiles (1563) + atomic rank chunks (782), task-interleaved --
    for (int task = bid; task < 2346; task += GRIDN) {
        int rem = task % 3;
        if (rem < 2) {
            int gid = (task / 3) * 2 + rem;
            if (gid < GT_GEMM)
                gemm_body<128, float, false, 128>(gid, x, W1, nullptr, t,
                                                  (short*)smem);
        } else {
            int g = task / 3;
            int e0 = g * 2048 + tid;
            int d[8], rv[8];
#pragma unroll
            for (int kk = 0; kk < 8; ++kk) {
                int e = e0 + kk * 256;
                if (e < N_EDGES) d[kk] = dstA[e];
            }
#pragma unroll
            for (int kk = 0; kk < 8; ++kk) {
                int e = e0 + kk * 256;
                if (e < N_EDGES) rv[kk] = atomicAdd(&cpad[d[kk]], 1);
            }
#pragma unroll
            for (int kk = 0; kk < 8; ++kk) {
                int e = e0 + kk * 256;
                if (e < N_EDGES) r[e] = rv[kk];
            }
        }
    }
    gsync(cbar, 1, tid);

    // ---- P2: per-chunk (512 nodes) local scan -> lrp, dinv, bsum; t pad zero --
    if (bid < NB2) {
        int* s = (int*)smem;
        int c = bid;
        int n0 = c * 512 + tid * 2;
        int va = (n0     < N_NODES) ? cpad[n0]     : 0;
        int vb = (n0 + 1 < N_NODES) ? cpad[n0 + 1] : 0;
        int sum2 = va + vb;
        s[tid] = sum2;
        __syncthreads();
        for (int off = 1; off < 256; off <<= 1) {
            int u = (tid >= off) ? s[tid - off] : 0;
            __syncthreads();
            s[tid] += u;
            __syncthreads();
        }
        int excl = s[tid] - sum2;
        if (n0 <= N_NODES) {
            lrp[n0] = excl;
            if (n0 < N_NODES) dinv[n0] = rsqrtf((float)(va + 1));
        }
        if (n0 + 1 <= N_NODES) {
            lrp[n0 + 1] = excl + va;
            if (n0 + 1 < N_NODES) dinv[n0 + 1] = rsqrtf((float)(vb + 1));
        }
        if (tid == 255) bsum[c] = s[255];
    }
    if (bid == GRIDN - 1 && tid < 64)
        t32[(size_t)N_NODES * 64 + tid] = 0;            // pad row for gather128
    gsync(cbar, 2, tid);

    // ---- P4: per-block boff scan (196) + rowptr finalize + fill + t prescale --
    {
        int* s = (int*)smem;
        int* sboff = (int*)smem + 288;
        int v = (tid < NB2) ? bsum[tid] : 0;
        s[tid] = v;
        __syncthreads();
        for (int off = 1; off < 256; off <<= 1) {
            int u = (tid >= off) ? s[tid - off] : 0;
            __syncthreads();
            s[tid] += u;
            __syncthreads();
        }
        if (tid < NB2) sboff[tid] = s[tid] - v;
        __syncthreads();
        for (int i = bid * 256 + tid; i <= N_NODES; i += GRIDN * 256)
            rowptr[i] = lrp[i] + sboff[i >> 9];
        for (int e = bid * 256 + tid; e < N_EDGES; e += GRIDN * 256) {
            int dd = dstA[e];
            col[lrp[dd] + sboff[dd >> 9] + r[e]] = srcA[e];
        }
        for (int idx = bid * 256 + tid; idx < N_NODES * 64; idx += GRIDN * 256) {
            int node = idx >> 6;
            uint32 p = t32[idx];
            float di = dinv[node];
            t32[idx] = pack2(bf_lo(p) * di, bf_hi(p) * di);
        }
    }
    gsync(cbar, 3, tid);

    // ---- P5: gather layer 1 ----
    gather128_phase<true>(rowptr, col, dinv, t32, b1, (uint32*)aggb, bid, tid, smem);
    gsync(cbar, 4, tid);

    // ---- P6: gemm2 (epilogue prescales by dinv) ----
    for (int gid = bid; gid < GT_GEMM; gid += GRIDN)
        gemm_body<128, ushort16, true, 128>(gid, aggb, W2, dinv, t, (short*)smem);
    gsync(cbar, 5, tid);

    // ---- P7: gather layer 2 ----
    gather128_phase<true>(rowptr, col, dinv, t32, b2, (uint32*)aggb, bid, tid, smem);
    gsync(cbar, 6, tid);

    // ---- P8: gemm3 -> dense z (reuses t buffer); z pad row zero ----
    if (bid == GRIDN - 1 && tid < 32)
        t32[(size_t)N_NODES * 32 + tid] = 0;            // z pad (disjoint from z)
    for (int gid = bid; gid < GT_GEMM; gid += GRIDN)
        gemm_body<64, ushort16, true, 64>(gid, aggb, W3, dinv, t, (short*)smem);
    gsync(cbar, 7, tid);

    // ---- P9: gather layer 3 (dense z) ----
    gather64_phase(rowptr, col, dinv, t32, b3, (uint32*)aggb, bid, tid, smem);
    gsync(cbar, 8, tid);

    // ---- P10: decode ----
    const ushort16* z = (const ushort16*)aggb;
    for (int e = bid * 256 + tid; e < N_EL; e += GRIDN * 256) {
        int a = eli[e];
        int bnd = eli[N_EL + e];
        const uint4* za = (const uint4*)(z + (size_t)a * 64);
        const uint4* zb = (const uint4*)(z + (size_t)bnd * 64);
        float acc = 0.0f;
#pragma unroll
        for (int i = 0; i < 8; ++i) {
            uint4 va = za[i], vb = zb[i];
            acc += bf_lo(va.x) * bf_lo(vb.x) + bf_hi(va.x) * bf_hi(vb.x);
            acc += bf_lo(va.y) * bf_lo(vb.y) + bf_hi(va.y) * bf_hi(vb.y);
            acc += bf_lo(va.z) * bf_lo(vb.z) + bf_hi(va.z) * bf_hi(vb.z);
            acc += bf_lo(va.w) * bf_lo(vb.w) + bf_hi(va.w) * bf_hi(vb.w);
        }
        out[e] = acc;
    }
}

extern "C" void kernel_launch(void* const* d_in, const int* in_sizes, int n_in,
                              void* d_out, int out_size, void* d_ws, size_t ws_size,
                              hipStream_t stream) {
    const float* x   = (const float*)d_in[0];
    const int*   ei  = (const int*)d_in[1];
    const int*   eli = (const int*)d_in[2];
    const float* W1  = (const float*)d_in[3];
    const float* b1  = (const float*)d_in[4];
    const float* W2  = (const float*)d_in[5];
    const float* b2  = (const float*)d_in[6];
    const float* W3  = (const float*)d_in[7];
    const float* b3  = (const float*)d_in[8];
    float* out = (float*)d_out;

    // workspace layout (bytes):
    //   dinv [0, 400K)    lrp [1M, +400,004)    rowptr [1.5M, +400,004)
    //   bsum [1.96M, +784)    cpad [2M, +400,000) cbar=cpad[100000]
    //   col [3M, +6.4M)   r [10M, +6.4M)
    //   t [20M, +25.6M+256)   aggb [48M, +25.6M)
    char* ws = (char*)d_ws;
    float*    dinv   = (float*)   (ws + 0);
    int*      lrp    = (int*)     (ws + (1024u << 10));
    int*      rowptr = (int*)     (ws + (1536u << 10));
    int*      bsum   = (int*)     (ws + (2007u << 10));
    int*      cpad   = (int*)     (ws + (2048u << 10));
    int*      col    = (int*)     (ws + (3072u << 10));
    int*      r      = (int*)     (ws + (10u << 20));
    ushort16* t      = (ushort16*)(ws + (20u << 20));
    ushort16* aggb   = (ushort16*)(ws + (48u << 20));
    int*      cbar   = cpad + N_NODES;

    // zero counters + barrier in one memset (100001 ints)
    hipMemsetAsync(cpad, 0, ((size_t)N_NODES + 1) * sizeof(int), stream);
    k_mega<<<GRIDN, 256, 0, stream>>>(x, ei, eli, W1, b1, W2, b2, W3, b3, out,
                                      dinv, lrp, rowptr, bsum, cpad, cbar,
                                      col, r, t, aggb);
}

// Round 7
// 444.001 us; speedup vs baseline: 3.8089x; 3.8089x over previous
//
#include <hip/hip_runtime.h>
#include <hip/hip_bf16.h>

#define N_NODES 100000
#define N_EDGES 1600000
#define N_EL    200000
// Round 21b (compile fix): same as round 21 — revert persistent kernel; base =
// round-2 multi-dispatch (431us) + proven grafts:
//  (1) 8B/lane gathers (round 4: 68->60.4us): g1 weighted via LDS dinv broadcast
//      (kills the prescale pass), g2 unweighted with pad row.
//  (2) gemm3 -> dense 64-wide z (halves g64 working set 25.6->12.8MB);
//      pad row zeroed by gemm3 block 0.
//  (3) fused scanF (round 3): 11 dispatches total.

#define CPAD 16                            // ints per counter line
#define GT_GEMM ((N_NODES + 63) / 64)      // 1563 gemm blocks (64 rows each)
#define GE_RANK ((N_EDGES + 255) / 256)    // 6250 rank blocks
#define NB2 ((N_NODES + 511) / 512)        // 196 scan blocks

typedef unsigned int uint32;
typedef unsigned short ushort16;
typedef __attribute__((ext_vector_type(8))) short short8;   // 8 bf16
typedef __attribute__((ext_vector_type(4))) float f32x4;

static __device__ __forceinline__ ushort16 f2bf(float f) {
    uint32 u = __float_as_uint(f);
    u += 0x7fffu + ((u >> 16) & 1u);      // RNE
    return (ushort16)(u >> 16);
}
static __device__ __forceinline__ float bf_lo(uint32 p) { return __uint_as_float(p << 16); }
static __device__ __forceinline__ float bf_hi(uint32 p) { return __uint_as_float(p & 0xffff0000u); }
static __device__ __forceinline__ uint32 pack2(float lo, float hi) {
    return (uint32)f2bf(lo) | ((uint32)f2bf(hi) << 16);
}

// ---------------- fused scan: local scan + dinv; last block scans block sums ----
__global__ void k_scanF(const int* __restrict__ cpad, int* __restrict__ lrp,
                        float* __restrict__ dinv, int* __restrict__ bsum,
                        int* __restrict__ boff, int* __restrict__ cnt) {
    __shared__ int s[512];
    __shared__ int lastflag;
    int t = threadIdx.x;
    int i = blockIdx.x * 512 + t;
    int v = (i < N_NODES) ? cpad[(size_t)i * CPAD] : 0;
    if (i < N_NODES) dinv[i] = rsqrtf((float)(v + 1));   // +1 self-loop
    s[t] = v;
    __syncthreads();
    for (int off = 1; off < 512; off <<= 1) {
        int u = (t >= off) ? s[t - off] : 0;
        __syncthreads();
        s[t] += u;
        __syncthreads();
    }
    if (i <= N_NODES) lrp[i] = s[t] - v;            // local exclusive scan
    if (t == 0) {
        __hip_atomic_store(&bsum[blockIdx.x], s[511], __ATOMIC_RELEASE,
                           __HIP_MEMORY_SCOPE_AGENT);
        int c = __hip_atomic_fetch_add(cnt, 1, __ATOMIC_ACQ_REL,
                                       __HIP_MEMORY_SCOPE_AGENT);
        lastflag = (c == NB2 - 1);
    }
    __syncthreads();
    if (!lastflag) return;
    int bv = (t < NB2) ? __hip_atomic_load(&bsum[t], __ATOMIC_ACQUIRE,
                                           __HIP_MEMORY_SCOPE_AGENT) : 0;
    s[t] = bv;
    __syncthreads();
    for (int off = 1; off < 512; off <<= 1) {
        int u = (t >= off) ? s[t - off] : 0;
        __syncthreads();
        s[t] += u;
        __syncthreads();
    }
    if (t < NB2) boff[t] = s[t] - bv;               // exclusive block offsets
}

// ---------------- fill: atomic-free CSR col fill ----------------
__global__ void k_fill2(const int* __restrict__ src, const int* __restrict__ dst,
                        const int* __restrict__ lrp, const int* __restrict__ boff,
                        const int* __restrict__ r, int* __restrict__ col) {
    int e = blockIdx.x * blockDim.x + threadIdx.x;
    if (e >= N_EDGES) return;
    int dd = dst[e];
    int pos = lrp[dd] + boff[dd >> 9] + r[e];
    __builtin_nontemporal_store(src[e], &col[pos]);
}

// ---------------- A-fragment loaders ----------------
static __device__ __forceinline__ short8 load_afrag(const float* arow, int off) {
    float4 a0 = *(const float4*)(arow + off);
    float4 a1 = *(const float4*)(arow + off + 4);
    short8 af;
    af[0] = (short)f2bf(a0.x); af[1] = (short)f2bf(a0.y);
    af[2] = (short)f2bf(a0.z); af[3] = (short)f2bf(a0.w);
    af[4] = (short)f2bf(a1.x); af[5] = (short)f2bf(a1.y);
    af[6] = (short)f2bf(a1.z); af[7] = (short)f2bf(a1.w);
    return af;
}
static __device__ __forceinline__ short8 load_afrag(const ushort16* arow, int off) {
    return *(const short8*)(arow + off);   // 16B aligned
}

// ---- MFMA GEMM body: C[n,0:D] = bf16( [dinv[n]] * (A[n,:128] @ W[128,D]) ) ----
template <int D, typename AT, bool SCALE, int OS>
static __device__ __forceinline__ void gemm_body(int bid, const AT* __restrict__ A,
        const float* __restrict__ W, const float* __restrict__ dinv,
        ushort16* __restrict__ C, short* sB) {
    constexpr int NT = D / 16;                 // 8 (D=128) or 4 (D=64)
    constexpr int LNT = (NT == 8) ? 3 : 2;
    int tid = threadIdx.x;

    // stage W -> LDS in B-fragment order; 8 consecutive shorts per thread ->
    // ds_write_b128, conflict-free.
    constexpr int COMBOS = 4 * 4 * NT * 16;    // 2048 / 1024
    for (int cc = tid; cc < COMBOS; cc += 256) {
        int nn = cc & 15;
        int nt = (cc >> 4) & (NT - 1);
        int q  = (cc >> (4 + LNT)) & 3;
        int kt = cc >> (6 + LNT);
        short8 pk;
#pragma unroll
        for (int j = 0; j < 8; ++j)
            pk[j] = (short)f2bf(W[(kt * 32 + q * 8 + j) * D + nt * 16 + nn]);
        *(short8*)&sB[(((kt * NT + nt) * 64) + q * 16 + nn) * 8] = pk;
    }
    __syncthreads();

    int w = tid >> 6;
    int l = tid & 63;
    int q = l >> 4;
    int nn15 = l & 15;
    int m0 = bid * 64 + w * 16;

    f32x4 acc[NT];
#pragma unroll
    for (int i = 0; i < NT; ++i) acc[i] = (f32x4){0.f, 0.f, 0.f, 0.f};

    int m = m0 + nn15;
    m = min(m, N_NODES - 1);                    // tail clamp (loads only)
    const AT* arow = A + (size_t)m * 128;

#pragma unroll
    for (int kt = 0; kt < 4; ++kt) {
        short8 af = load_afrag(arow, kt * 32 + q * 8);
#pragma unroll
        for (int nt = 0; nt < NT; ++nt) {
            short8 bf = *(const short8*)&sB[((kt * NT + nt) * 64 + l) * 8];
            acc[nt] = __builtin_amdgcn_mfma_f32_16x16x32_bf16(af, bf, acc[nt], 0, 0, 0);
        }
    }

    float4 dvv;
    if constexpr (SCALE) dvv = *(const float4*)(dinv + m0 + 4 * q);
    const float* dvp = (const float*)&dvv;
#pragma unroll
    for (int nt = 0; nt < NT; ++nt) {
#pragma unroll
        for (int rr = 0; rr < 4; ++rr) {
            int node = m0 + q * 4 + rr;
            if (node < N_NODES) {
                float val = acc[nt][rr];
                if constexpr (SCALE) val *= dvp[rr];
                C[(size_t)node * OS + nt * 16 + nn15] = f2bf(val);
            }
        }
    }
}

// PADZ: block 0 zeroes the pad row (row N_NODES of an OS-wide output).
template <int D, typename AT, bool SCALE, int OS, bool PADZ>
__global__ __launch_bounds__(256, 5) void k_gemm_mfma(const AT* __restrict__ A,
        const float* __restrict__ W, const float* __restrict__ dinv,
        ushort16* __restrict__ C) {
    __shared__ short sB[4 * (D / 16) * 64 * 8];
    if (PADZ && blockIdx.x == 0 && threadIdx.x < OS / 2)
        ((uint32*)C)[(size_t)N_NODES * (OS / 2) + threadIdx.x] = 0;
    gemm_body<D, AT, SCALE, OS>(blockIdx.x, A, W, dinv, C, sB);
}

// ------- fat1: GEMM1 + rank (1 atomic/thread), bid%5 interleaved ----------------
__global__ __launch_bounds__(256, 5) void k_fat1(const float* __restrict__ A,
        const float* __restrict__ W, ushort16* __restrict__ C,
        const int* __restrict__ dst, int* __restrict__ cpad, int* __restrict__ r) {
    __shared__ short sB[4 * 8 * 64 * 8];
    unsigned bid = blockIdx.x;
    unsigned g = bid / 5u;
    unsigned rem = bid - g * 5u;
    if (rem == 0u) {                            // 1563 gemm blocks
        gemm_body<128, float, false, 128>(g, A, W, nullptr, C, sB);
    } else {                                    // 6250 rank blocks
        unsigned rid = g * 4u + rem - 1u;
        unsigned e = rid * 256u + threadIdx.x;
        if (e < N_EDGES) r[e] = atomicAdd(&cpad[(size_t)dst[e] * CPAD], 1);
    }
}

// ---------------- gather, D=128, 8B/lane, 2 rows per load instruction -----------
// WEIGHTED: t unscaled, weight = dinv[src] from LDS broadcast (pads weight 0).
// !WEIGHTED: t prescaled; pads -> zero row t[N_NODES].
template <bool RELU, bool WEIGHTED>
__global__ void k_gather128(const int* __restrict__ lrp, const int* __restrict__ boff,
                            const int* __restrict__ col, const float* __restrict__ dinv,
                            const uint32* __restrict__ t, const float* __restrict__ b,
                            uint32* __restrict__ outbuf) {
    __shared__ int   sc[4][64];
    __shared__ float sd[4][64];
    int tid = threadIdx.x;
    unsigned wid = (blockIdx.x * 256u + tid) >> 6;
    if (wid >= N_NODES) return;
    int w = tid >> 6;
    int lane = tid & 63;
    int h = lane >> 5;              // which row of each pair this half-wave reads
    int k = lane & 31;              // uint2 index within row (dims 4k..4k+3)
    int beg = lrp[wid] + boff[wid >> 9];
    int end = lrp[wid + 1] + boff[(wid + 1) >> 9];
    float di = dinv[wid];
    float a0 = 0.f, a1 = 0.f, a2 = 0.f, a3 = 0.f;
    if (h == 0) {                    // self-loop term counted once
        uint2 p = ((const uint2*)(t + (size_t)wid * 64))[k];
        float sw = WEIGHTED ? di : 1.0f;
        a0 = sw * bf_lo(p.x); a1 = sw * bf_hi(p.x);
        a2 = sw * bf_lo(p.y); a3 = sw * bf_hi(p.y);
    }
    for (int base = beg; base < end; base += 64) {
        int cnt = min(end - base, 64);
        int c = WEIGHTED ? 0 : N_NODES;
        if (lane < cnt) c = col[base + lane];
        sc[w][lane] = c;             // same-wave LDS, no barrier needed
        if (WEIGHTED) sd[w][lane] = (lane < cnt) ? dinv[c] : 0.f;
        int nb8 = (cnt + 7) >> 3;
        for (int j8 = 0; j8 < nb8; ++j8) {
            int j = j8 << 3;
            int r0 = sc[w][j + 0 + h];
            int r1 = sc[w][j + 2 + h];
            int r2 = sc[w][j + 4 + h];
            int r3 = sc[w][j + 6 + h];
            uint2 v0 = ((const uint2*)(t + (size_t)r0 * 64))[k];
            uint2 v1 = ((const uint2*)(t + (size_t)r1 * 64))[k];
            uint2 v2 = ((const uint2*)(t + (size_t)r2 * 64))[k];
            uint2 v3 = ((const uint2*)(t + (size_t)r3 * 64))[k];
            if (WEIGHTED) {
                float d0 = sd[w][j + 0 + h];
                float d1 = sd[w][j + 2 + h];
                float d2 = sd[w][j + 4 + h];
                float d3 = sd[w][j + 6 + h];
                a0 = fmaf(d0, bf_lo(v0.x), a0); a1 = fmaf(d0, bf_hi(v0.x), a1);
                a2 = fmaf(d0, bf_lo(v0.y), a2); a3 = fmaf(d0, bf_hi(v0.y), a3);
                a0 = fmaf(d1, bf_lo(v1.x), a0); a1 = fmaf(d1, bf_hi(v1.x), a1);
                a2 = fmaf(d1, bf_lo(v1.y), a2); a3 = fmaf(d1, bf_hi(v1.y), a3);
                a0 = fmaf(d2, bf_lo(v2.x), a0); a1 = fmaf(d2, bf_hi(v2.x), a1);
                a2 = fmaf(d2, bf_lo(v2.y), a2); a3 = fmaf(d2, bf_hi(v2.y), a3);
                a0 = fmaf(d3, bf_lo(v3.x), a0); a1 = fmaf(d3, bf_hi(v3.x), a1);
                a2 = fmaf(d3, bf_lo(v3.y), a2); a3 = fmaf(d3, bf_hi(v3.y), a3);
            } else {
                a0 += (bf_lo(v0.x) + bf_lo(v1.x)) + (bf_lo(v2.x) + bf_lo(v3.x));
                a1 += (bf_hi(v0.x) + bf_hi(v1.x)) + (bf_hi(v2.x) + bf_hi(v3.x));
                a2 += (bf_lo(v0.y) + bf_lo(v1.y)) + (bf_lo(v2.y) + bf_lo(v3.y));
                a3 += (bf_hi(v0.y) + bf_hi(v1.y)) + (bf_hi(v2.y) + bf_hi(v3.y));
            }
        }
    }
    a0 += __shfl_xor(a0, 32);
    a1 += __shfl_xor(a1, 32);
    a2 += __shfl_xor(a2, 32);
    a3 += __shfl_xor(a3, 32);
    if (h == 0) {
        float4 bb = ((const float4*)b)[k];
        float o0 = fmaf(di, a0, bb.x);
        float o1 = fmaf(di, a1, bb.y);
        float o2 = fmaf(di, a2, bb.z);
        float o3 = fmaf(di, a3, bb.w);
        if (RELU) {
            o0 = fmaxf(o0, 0.f); o1 = fmaxf(o1, 0.f);
            o2 = fmaxf(o2, 0.f); o3 = fmaxf(o3, 0.f);
        }
        unsigned long long pv = (unsigned long long)pack2(o0, o1)
                              | ((unsigned long long)pack2(o2, o3) << 32);
        __builtin_nontemporal_store(pv,
            (unsigned long long*)(outbuf + (size_t)wid * 64) + k);
    }
}

// ---- gather, D=64 dense (stride 32 uint32): 4 rows per load instr --------------
__global__ void k_gather64(const int* __restrict__ lrp, const int* __restrict__ boff,
                           const int* __restrict__ col, const float* __restrict__ dinv,
                           const uint32* __restrict__ z, const float* __restrict__ b,
                           uint32* __restrict__ outbuf) {
    __shared__ int sc[4][64];
    int tid = threadIdx.x;
    unsigned wid = (blockIdx.x * 256u + tid) >> 6;
    if (wid >= N_NODES) return;
    int w = tid >> 6;
    int lane = tid & 63;
    int h = lane >> 4;              // 0..3: which row of each quad
    int k = lane & 15;              // uint2 index (dims 4k..4k+3 of 64)
    int beg = lrp[wid] + boff[wid >> 9];
    int end = lrp[wid + 1] + boff[(wid + 1) >> 9];
    float a0 = 0.f, a1 = 0.f, a2 = 0.f, a3 = 0.f;
    if (h == 0) {
        uint2 p = ((const uint2*)(z + (size_t)wid * 32))[k];
        a0 = bf_lo(p.x); a1 = bf_hi(p.x); a2 = bf_lo(p.y); a3 = bf_hi(p.y);
    }
    for (int base = beg; base < end; base += 64) {
        int cnt = min(end - base, 64);
        int c = N_NODES;
        if (lane < cnt) c = col[base + lane];
        sc[w][lane] = c;
        int nb8 = (cnt + 7) >> 3;
        for (int j8 = 0; j8 < nb8; ++j8) {
            int j = j8 << 3;
            int r0 = sc[w][j + h];
            int r1 = sc[w][j + 4 + h];
            uint2 v0 = ((const uint2*)(z + (size_t)r0 * 32))[k];
            uint2 v1 = ((const uint2*)(z + (size_t)r1 * 32))[k];
            a0 += bf_lo(v0.x) + bf_lo(v1.x);
            a1 += bf_hi(v0.x) + bf_hi(v1.x);
            a2 += bf_lo(v0.y) + bf_lo(v1.y);
            a3 += bf_hi(v0.y) + bf_hi(v1.y);
        }
    }
    a0 += __shfl_xor(a0, 16); a0 += __shfl_xor(a0, 32);
    a1 += __shfl_xor(a1, 16); a1 += __shfl_xor(a1, 32);
    a2 += __shfl_xor(a2, 16); a2 += __shfl_xor(a2, 32);
    a3 += __shfl_xor(a3, 16); a3 += __shfl_xor(a3, 32);
    if (h == 0) {
        float di = dinv[wid];
        float4 bb = ((const float4*)b)[k];
        float o0 = fmaf(di, a0, bb.x);
        float o1 = fmaf(di, a1, bb.y);
        float o2 = fmaf(di, a2, bb.z);
        float o3 = fmaf(di, a3, bb.w);
        unsigned long long pv = (unsigned long long)pack2(o0, o1)
                              | ((unsigned long long)pack2(o2, o3) << 32);
        __builtin_nontemporal_store(pv,
            (unsigned long long*)(outbuf + (size_t)wid * 32) + k);
    }
}

// ---------------- decode: z is bf16 [N x 64] ----------------
__global__ void k_decode(const int* __restrict__ eli, const ushort16* __restrict__ z,
                         float* __restrict__ out) {
    int e = blockIdx.x * blockDim.x + threadIdx.x;
    if (e >= N_EL) return;
    int a = eli[e];
    int b = eli[N_EL + e];
    const uint4* za = (const uint4*)(z + (size_t)a * 64);
    const uint4* zb = (const uint4*)(z + (size_t)b * 64);
    float acc = 0.0f;
#pragma unroll
    for (int i = 0; i < 8; ++i) {
        uint4 va = za[i], vb = zb[i];
        acc += bf_lo(va.x) * bf_lo(vb.x) + bf_hi(va.x) * bf_hi(vb.x);
        acc += bf_lo(va.y) * bf_lo(vb.y) + bf_hi(va.y) * bf_hi(vb.y);
        acc += bf_lo(va.z) * bf_lo(vb.z) + bf_hi(va.z) * bf_hi(vb.z);
        acc += bf_lo(va.w) * bf_lo(vb.w) + bf_hi(va.w) * bf_hi(vb.w);
    }
    out[e] = acc;
}

extern "C" void kernel_launch(void* const* d_in, const int* in_sizes, int n_in,
                              void* d_out, int out_size, void* d_ws, size_t ws_size,
                              hipStream_t stream) {
    const float* x   = (const float*)d_in[0];
    const int*   ei  = (const int*)d_in[1];
    const int*   eli = (const int*)d_in[2];
    const float* W1  = (const float*)d_in[3];
    const float* b1  = (const float*)d_in[4];
    const float* W2  = (const float*)d_in[5];
    const float* b2  = (const float*)d_in[6];
    const float* W3  = (const float*)d_in[7];
    const float* b3  = (const float*)d_in[8];
    float* out = (float*)d_out;

    const int* srcA = ei;
    const int* dstA = ei + N_EDGES;

    // workspace layout (bytes):
    //   dinv [0, 400K)   lrp [1M, +400,004)
    //   bsum [1888K, +784)  boff [1896K, +784)
    //   col [2M, +6.4M)   r [9M, +6.4M)
    //   t   [16M, +25.6M+256)  bf16 N x 128 (+ zero pad row); layer-3 z dense
    //                          N x 64 lives in the same buffer (pad at N*128B)
    //   aggb [48M, +25.6M)  bf16 N x 128 (layers), N x 64 (final agg z)
    //   cpad [80M, +6.4M+64)  line-padded counters + scanF arrival counter
    char* ws = (char*)d_ws;
    float*    dinv   = (float*)   (ws + 0);
    int*      lrp    = (int*)     (ws + (1024u << 10));
    int*      bsum   = (int*)     (ws + (1888u << 10));
    int*      boff   = (int*)     (ws + (1896u << 10));
    int*      col    = (int*)     (ws + (2048u << 10));
    int*      r      = (int*)     (ws + (9u << 20));
    ushort16* t      = (ushort16*)(ws + (16u << 20));
    ushort16* aggb   = (ushort16*)(ws + (48u << 20));
    int*      cpad   = (int*)     (ws + (80u << 20));
    int*      cnt    = cpad + (size_t)N_NODES * CPAD;     // covered by memset

    const int B = 256;
    const int gG  = (N_NODES * 64 + B - 1) / B;   // 25000
    const int gEL = (N_EL + B - 1) / B;

    // ---- CSR build overlapped with GEMM1 (interleaved block roles) ----
    hipMemsetAsync(cpad, 0, ((size_t)N_NODES * CPAD + 16) * sizeof(int), stream);
    hipMemsetAsync((char*)t + (size_t)N_NODES * 256, 0, 256, stream);  // g2 pad row
    k_fat1<<<GT_GEMM + GE_RANK, B, 0, stream>>>(x, W1, t, dstA, cpad, r);
    k_scanF<<<NB2, 512, 0, stream>>>(cpad, lrp, dinv, bsum, boff, cnt);
    k_fill2<<<GE_RANK, B, 0, stream>>>(srcA, dstA, lrp, boff, r, col);

    // ---- layer 1 aggregation (weighted: dinv[src] from LDS broadcast) ----
    k_gather128<true, true><<<gG, B, 0, stream>>>(lrp, boff, col, dinv,
                                                  (const uint32*)t, b1, (uint32*)aggb);
    // ---- layer 2 (epilogue prescales t by dinv) ----
    k_gemm_mfma<128, ushort16, true, 128, false><<<GT_GEMM, B, 0, stream>>>(
        aggb, W2, dinv, t);
    k_gather128<true, false><<<gG, B, 0, stream>>>(lrp, boff, col, dinv,
                                                   (const uint32*)t, b2, (uint32*)aggb);
    // ---- layer 3: dense 64-wide z (pad row zeroed by gemm3 block 0) ----
    k_gemm_mfma<64, ushort16, true, 64, true><<<GT_GEMM, B, 0, stream>>>(
        aggb, W3, dinv, t);
    k_gather64<<<gG, B, 0, stream>>>(lrp, boff, col, dinv, (const uint32*)t, b3,
                                     (uint32*)aggb);

    // ---- decode ----
    k_decode<<<gEL, B, 0, stream>>>(eli, aggb, out);
}

// Round 9
// 439.347 us; speedup vs baseline: 3.8493x; 1.0106x over previous
//
#include <hip/hip_runtime.h>
#include <hip/hip_bf16.h>

#define N_NODES 100000
#define N_EDGES 1600000
#define N_EL    200000
// Round 22b (compile fix: nontemporal store needs ext_vector_type, not HIP uint4).
// 16B/lane (uint4) gathers — 4 rows/load-instr for D=128 (16 lanes/row),
// 8 rows/load-instr for D=64 (8 lanes/row). Halves VMEM instruction count vs 8B
// (which gave -11% over 4B in round 4). CPAD 16->1 (atomic wall is count-bound;
// dense counters -> 400KB memset + coalesced scanF reads). Pad-row zeroing folded
// into fat1. Everything else = round 21b.

#define CPAD 1
#define GT_GEMM ((N_NODES + 63) / 64)      // 1563 gemm blocks (64 rows each)
#define GE_RANK ((N_EDGES + 255) / 256)    // 6250 rank blocks
#define NB2 ((N_NODES + 511) / 512)        // 196 scan blocks

typedef unsigned int uint32;
typedef unsigned short ushort16;
typedef __attribute__((ext_vector_type(8))) short short8;   // 8 bf16
typedef __attribute__((ext_vector_type(4))) float f32x4;
typedef __attribute__((ext_vector_type(4))) unsigned int u32x4;

static __device__ __forceinline__ ushort16 f2bf(float f) {
    uint32 u = __float_as_uint(f);
    u += 0x7fffu + ((u >> 16) & 1u);      // RNE
    return (ushort16)(u >> 16);
}
static __device__ __forceinline__ float bf_lo(uint32 p) { return __uint_as_float(p << 16); }
static __device__ __forceinline__ float bf_hi(uint32 p) { return __uint_as_float(p & 0xffff0000u); }
static __device__ __forceinline__ uint32 pack2(float lo, float hi) {
    return (uint32)f2bf(lo) | ((uint32)f2bf(hi) << 16);
}

// ---------------- fused scan: local scan + dinv; last block scans block sums ----
__global__ void k_scanF(const int* __restrict__ cpad, int* __restrict__ lrp,
                        float* __restrict__ dinv, int* __restrict__ bsum,
                        int* __restrict__ boff, int* __restrict__ cnt) {
    __shared__ int s[512];
    __shared__ int lastflag;
    int t = threadIdx.x;
    int i = blockIdx.x * 512 + t;
    int v = (i < N_NODES) ? cpad[i] : 0;
    if (i < N_NODES) dinv[i] = rsqrtf((float)(v + 1));   // +1 self-loop
    s[t] = v;
    __syncthreads();
    for (int off = 1; off < 512; off <<= 1) {
        int u = (t >= off) ? s[t - off] : 0;
        __syncthreads();
        s[t] += u;
        __syncthreads();
    }
    if (i <= N_NODES) lrp[i] = s[t] - v;            // local exclusive scan
    if (t == 0) {
        __hip_atomic_store(&bsum[blockIdx.x], s[511], __ATOMIC_RELEASE,
                           __HIP_MEMORY_SCOPE_AGENT);
        int c = __hip_atomic_fetch_add(cnt, 1, __ATOMIC_ACQ_REL,
                                       __HIP_MEMORY_SCOPE_AGENT);
        lastflag = (c == NB2 - 1);
    }
    __syncthreads();
    if (!lastflag) return;
    int bv = (t < NB2) ? __hip_atomic_load(&bsum[t], __ATOMIC_ACQUIRE,
                                           __HIP_MEMORY_SCOPE_AGENT) : 0;
    s[t] = bv;
    __syncthreads();
    for (int off = 1; off < 512; off <<= 1) {
        int u = (t >= off) ? s[t - off] : 0;
        __syncthreads();
        s[t] += u;
        __syncthreads();
    }
    if (t < NB2) boff[t] = s[t] - bv;               // exclusive block offsets
}

// ---------------- fill: atomic-free CSR col fill ----------------
__global__ void k_fill2(const int* __restrict__ src, const int* __restrict__ dst,
                        const int* __restrict__ lrp, const int* __restrict__ boff,
                        const int* __restrict__ r, int* __restrict__ col) {
    int e = blockIdx.x * blockDim.x + threadIdx.x;
    if (e >= N_EDGES) return;
    int dd = dst[e];
    int pos = lrp[dd] + boff[dd >> 9] + r[e];
    __builtin_nontemporal_store(src[e], &col[pos]);
}

// ---------------- A-fragment loaders ----------------
static __device__ __forceinline__ short8 load_afrag(const float* arow, int off) {
    float4 a0 = *(const float4*)(arow + off);
    float4 a1 = *(const float4*)(arow + off + 4);
    short8 af;
    af[0] = (short)f2bf(a0.x); af[1] = (short)f2bf(a0.y);
    af[2] = (short)f2bf(a0.z); af[3] = (short)f2bf(a0.w);
    af[4] = (short)f2bf(a1.x); af[5] = (short)f2bf(a1.y);
    af[6] = (short)f2bf(a1.z); af[7] = (short)f2bf(a1.w);
    return af;
}
static __device__ __forceinline__ short8 load_afrag(const ushort16* arow, int off) {
    return *(const short8*)(arow + off);   // 16B aligned
}

// ---- MFMA GEMM body: C[n,0:D] = bf16( [dinv[n]] * (A[n,:128] @ W[128,D]) ) ----
template <int D, typename AT, bool SCALE, int OS>
static __device__ __forceinline__ void gemm_body(int bid, const AT* __restrict__ A,
        const float* __restrict__ W, const float* __restrict__ dinv,
        ushort16* __restrict__ C, short* sB) {
    constexpr int NT = D / 16;                 // 8 (D=128) or 4 (D=64)
    constexpr int LNT = (NT == 8) ? 3 : 2;
    int tid = threadIdx.x;

    // stage W -> LDS in B-fragment order; 8 consecutive shorts per thread ->
    // ds_write_b128, conflict-free.
    constexpr int COMBOS = 4 * 4 * NT * 16;    // 2048 / 1024
    for (int cc = tid; cc < COMBOS; cc += 256) {
        int nn = cc & 15;
        int nt = (cc >> 4) & (NT - 1);
        int q  = (cc >> (4 + LNT)) & 3;
        int kt = cc >> (6 + LNT);
        short8 pk;
#pragma unroll
        for (int j = 0; j < 8; ++j)
            pk[j] = (short)f2bf(W[(kt * 32 + q * 8 + j) * D + nt * 16 + nn]);
        *(short8*)&sB[(((kt * NT + nt) * 64) + q * 16 + nn) * 8] = pk;
    }
    __syncthreads();

    int w = tid >> 6;
    int l = tid & 63;
    int q = l >> 4;
    int nn15 = l & 15;
    int m0 = bid * 64 + w * 16;

    f32x4 acc[NT];
#pragma unroll
    for (int i = 0; i < NT; ++i) acc[i] = (f32x4){0.f, 0.f, 0.f, 0.f};

    int m = m0 + nn15;
    m = min(m, N_NODES - 1);                    // tail clamp (loads only)
    const AT* arow = A + (size_t)m * 128;

#pragma unroll
    for (int kt = 0; kt < 4; ++kt) {
        short8 af = load_afrag(arow, kt * 32 + q * 8);
#pragma unroll
        for (int nt = 0; nt < NT; ++nt) {
            short8 bf = *(const short8*)&sB[((kt * NT + nt) * 64 + l) * 8];
            acc[nt] = __builtin_amdgcn_mfma_f32_16x16x32_bf16(af, bf, acc[nt], 0, 0, 0);
        }
    }

    float4 dvv;
    if constexpr (SCALE) dvv = *(const float4*)(dinv + m0 + 4 * q);
    const float* dvp = (const float*)&dvv;
#pragma unroll
    for (int nt = 0; nt < NT; ++nt) {
#pragma unroll
        for (int rr = 0; rr < 4; ++rr) {
            int node = m0 + q * 4 + rr;
            if (node < N_NODES) {
                float val = acc[nt][rr];
                if constexpr (SCALE) val *= dvp[rr];
                C[(size_t)node * OS + nt * 16 + nn15] = f2bf(val);
            }
        }
    }
}

// PADZ: block 0 zeroes the pad row (row N_NODES of an OS-wide output).
template <int D, typename AT, bool SCALE, int OS, bool PADZ>
__global__ __launch_bounds__(256, 5) void k_gemm_mfma(const AT* __restrict__ A,
        const float* __restrict__ W, const float* __restrict__ dinv,
        ushort16* __restrict__ C) {
    __shared__ short sB[4 * (D / 16) * 64 * 8];
    if (PADZ && blockIdx.x == 0 && threadIdx.x < OS / 2)
        ((uint32*)C)[(size_t)N_NODES * (OS / 2) + threadIdx.x] = 0;
    gemm_body<D, AT, SCALE, OS>(blockIdx.x, A, W, dinv, C, sB);
}

// ------- fat1: GEMM1 + rank (1 atomic/thread), bid%5 interleaved ----------------
// bid==1 (first rank block) also zeroes the t pad row for gather2.
__global__ __launch_bounds__(256, 5) void k_fat1(const float* __restrict__ A,
        const float* __restrict__ W, ushort16* __restrict__ C,
        const int* __restrict__ dst, int* __restrict__ cpad, int* __restrict__ r) {
    __shared__ short sB[4 * 8 * 64 * 8];
    unsigned bid = blockIdx.x;
    unsigned g = bid / 5u;
    unsigned rem = bid - g * 5u;
    if (rem == 0u) {                            // 1563 gemm blocks
        gemm_body<128, float, false, 128>(g, A, W, nullptr, C, sB);
    } else {                                    // 6250 rank blocks
        if (bid == 1u && threadIdx.x < 64)      // zero pad row t[N_NODES]
            ((uint32*)C)[(size_t)N_NODES * 64 + threadIdx.x] = 0;
        unsigned rid = g * 4u + rem - 1u;
        unsigned e = rid * 256u + threadIdx.x;
        if (e < N_EDGES) r[e] = atomicAdd(&cpad[dst[e]], 1);
    }
}

// ---------------- gather, D=128, 16B/lane: 16 lanes/row, 4 rows per load --------
// WEIGHTED: t unscaled, weight = dinv[src] from LDS broadcast (pads weight 0).
// !WEIGHTED: t prescaled; pads -> zero row t[N_NODES].
template <bool RELU, bool WEIGHTED>
__global__ void k_gather128(const int* __restrict__ lrp, const int* __restrict__ boff,
                            const int* __restrict__ col, const float* __restrict__ dinv,
                            const uint32* __restrict__ t, const float* __restrict__ b,
                            uint32* __restrict__ outbuf) {
    __shared__ int   sc[4][64];
    __shared__ float sd[4][64];
    int tid = threadIdx.x;
    unsigned wid = (blockIdx.x * 256u + tid) >> 6;
    if (wid >= N_NODES) return;
    int w = tid >> 6;
    int lane = tid & 63;
    int h = lane >> 4;              // 0..3: which row of each quad
    int k = lane & 15;              // uint4 index within row (dims 8k..8k+7)
    int beg = lrp[wid] + boff[wid >> 9];
    int end = lrp[wid + 1] + boff[(wid + 1) >> 9];
    float di = dinv[wid];
    float a0 = 0.f, a1 = 0.f, a2 = 0.f, a3 = 0.f;
    float a4 = 0.f, a5 = 0.f, a6 = 0.f, a7 = 0.f;
    if (h == 0) {                    // self-loop term counted once
        uint4 p = ((const uint4*)(t + (size_t)wid * 64))[k];
        float sw = WEIGHTED ? di : 1.0f;
        a0 = sw * bf_lo(p.x); a1 = sw * bf_hi(p.x);
        a2 = sw * bf_lo(p.y); a3 = sw * bf_hi(p.y);
        a4 = sw * bf_lo(p.z); a5 = sw * bf_hi(p.z);
        a6 = sw * bf_lo(p.w); a7 = sw * bf_hi(p.w);
    }
    for (int base = beg; base < end; base += 64) {
        int cnt = min(end - base, 64);
        int c = WEIGHTED ? 0 : N_NODES;
        if (lane < cnt) c = col[base + lane];
        sc[w][lane] = c;             // same-wave LDS, no barrier needed
        if (WEIGHTED) sd[w][lane] = (lane < cnt) ? dinv[c] : 0.f;
        int nb8 = (cnt + 7) >> 3;
        for (int j8 = 0; j8 < nb8; ++j8) {
            int j = j8 << 3;
            int r0 = sc[w][j + h];
            int r1 = sc[w][j + 4 + h];
            uint4 v0 = ((const uint4*)(t + (size_t)r0 * 64))[k];
            uint4 v1 = ((const uint4*)(t + (size_t)r1 * 64))[k];
            if (WEIGHTED) {
                float d0 = sd[w][j + h];
                float d1 = sd[w][j + 4 + h];
                a0 = fmaf(d0, bf_lo(v0.x), a0); a1 = fmaf(d0, bf_hi(v0.x), a1);
                a2 = fmaf(d0, bf_lo(v0.y), a2); a3 = fmaf(d0, bf_hi(v0.y), a3);
                a4 = fmaf(d0, bf_lo(v0.z), a4); a5 = fmaf(d0, bf_hi(v0.z), a5);
                a6 = fmaf(d0, bf_lo(v0.w), a6); a7 = fmaf(d0, bf_hi(v0.w), a7);
                a0 = fmaf(d1, bf_lo(v1.x), a0); a1 = fmaf(d1, bf_hi(v1.x), a1);
                a2 = fmaf(d1, bf_lo(v1.y), a2); a3 = fmaf(d1, bf_hi(v1.y), a3);
                a4 = fmaf(d1, bf_lo(v1.z), a4); a5 = fmaf(d1, bf_hi(v1.z), a5);
                a6 = fmaf(d1, bf_lo(v1.w), a6); a7 = fmaf(d1, bf_hi(v1.w), a7);
            } else {
                a0 += bf_lo(v0.x) + bf_lo(v1.x);
                a1 += bf_hi(v0.x) + bf_hi(v1.x);
                a2 += bf_lo(v0.y) + bf_lo(v1.y);
                a3 += bf_hi(v0.y) + bf_hi(v1.y);
                a4 += bf_lo(v0.z) + bf_lo(v1.z);
                a5 += bf_hi(v0.z) + bf_hi(v1.z);
                a6 += bf_lo(v0.w) + bf_lo(v1.w);
                a7 += bf_hi(v0.w) + bf_hi(v1.w);
            }
        }
    }
    a0 += __shfl_xor(a0, 16); a0 += __shfl_xor(a0, 32);
    a1 += __shfl_xor(a1, 16); a1 += __shfl_xor(a1, 32);
    a2 += __shfl_xor(a2, 16); a2 += __shfl_xor(a2, 32);
    a3 += __shfl_xor(a3, 16); a3 += __shfl_xor(a3, 32);
    a4 += __shfl_xor(a4, 16); a4 += __shfl_xor(a4, 32);
    a5 += __shfl_xor(a5, 16); a5 += __shfl_xor(a5, 32);
    a6 += __shfl_xor(a6, 16); a6 += __shfl_xor(a6, 32);
    a7 += __shfl_xor(a7, 16); a7 += __shfl_xor(a7, 32);
    if (h == 0) {
        float4 ba = ((const float4*)b)[2 * k];
        float4 bb = ((const float4*)b)[2 * k + 1];
        float o0 = fmaf(di, a0, ba.x);
        float o1 = fmaf(di, a1, ba.y);
        float o2 = fmaf(di, a2, ba.z);
        float o3 = fmaf(di, a3, ba.w);
        float o4 = fmaf(di, a4, bb.x);
        float o5 = fmaf(di, a5, bb.y);
        float o6 = fmaf(di, a6, bb.z);
        float o7 = fmaf(di, a7, bb.w);
        if (RELU) {
            o0 = fmaxf(o0, 0.f); o1 = fmaxf(o1, 0.f);
            o2 = fmaxf(o2, 0.f); o3 = fmaxf(o3, 0.f);
            o4 = fmaxf(o4, 0.f); o5 = fmaxf(o5, 0.f);
            o6 = fmaxf(o6, 0.f); o7 = fmaxf(o7, 0.f);
        }
        u32x4 pv;
        pv[0] = pack2(o0, o1); pv[1] = pack2(o2, o3);
        pv[2] = pack2(o4, o5); pv[3] = pack2(o6, o7);
        __builtin_nontemporal_store(pv, (u32x4*)(outbuf + (size_t)wid * 64) + k);
    }
}

// ---- gather, D=64 dense (stride 32 uint32), 16B/lane: 8 lanes/row, 8 rows/load -
__global__ void k_gather64(const int* __restrict__ lrp, const int* __restrict__ boff,
                           const int* __restrict__ col, const float* __restrict__ dinv,
                           const uint32* __restrict__ z, const float* __restrict__ b,
                           uint32* __restrict__ outbuf) {
    __shared__ int sc[4][64];
    int tid = threadIdx.x;
    unsigned wid = (blockIdx.x * 256u + tid) >> 6;
    if (wid >= N_NODES) return;
    int w = tid >> 6;
    int lane = tid & 63;
    int h = lane >> 3;              // 0..7: which row of each octet
    int k = lane & 7;               // uint4 index (dims 8k..8k+7 of 64)
    int beg = lrp[wid] + boff[wid >> 9];
    int end = lrp[wid + 1] + boff[(wid + 1) >> 9];
    float a0 = 0.f, a1 = 0.f, a2 = 0.f, a3 = 0.f;
    float a4 = 0.f, a5 = 0.f, a6 = 0.f, a7 = 0.f;
    if (h == 0) {
        uint4 p = ((const uint4*)(z + (size_t)wid * 32))[k];
        a0 = bf_lo(p.x); a1 = bf_hi(p.x); a2 = bf_lo(p.y); a3 = bf_hi(p.y);
        a4 = bf_lo(p.z); a5 = bf_hi(p.z); a6 = bf_lo(p.w); a7 = bf_hi(p.w);
    }
    for (int base = beg; base < end; base += 64) {
        int cnt = min(end - base, 64);
        int c = N_NODES;
        if (lane < cnt) c = col[base + lane];
        sc[w][lane] = c;
        int nb8 = (cnt + 7) >> 3;
        for (int j8 = 0; j8 < nb8; ++j8) {
            int r0 = sc[w][(j8 << 3) + h];
            uint4 v0 = ((const uint4*)(z + (size_t)r0 * 32))[k];
            a0 += bf_lo(v0.x); a1 += bf_hi(v0.x);
            a2 += bf_lo(v0.y); a3 += bf_hi(v0.y);
            a4 += bf_lo(v0.z); a5 += bf_hi(v0.z);
            a6 += bf_lo(v0.w); a7 += bf_hi(v0.w);
        }
    }
    a0 += __shfl_xor(a0, 8); a0 += __shfl_xor(a0, 16); a0 += __shfl_xor(a0, 32);
    a1 += __shfl_xor(a1, 8); a1 += __shfl_xor(a1, 16); a1 += __shfl_xor(a1, 32);
    a2 += __shfl_xor(a2, 8); a2 += __shfl_xor(a2, 16); a2 += __shfl_xor(a2, 32);
    a3 += __shfl_xor(a3, 8); a3 += __shfl_xor(a3, 16); a3 += __shfl_xor(a3, 32);
    a4 += __shfl_xor(a4, 8); a4 += __shfl_xor(a4, 16); a4 += __shfl_xor(a4, 32);
    a5 += __shfl_xor(a5, 8); a5 += __shfl_xor(a5, 16); a5 += __shfl_xor(a5, 32);
    a6 += __shfl_xor(a6, 8); a6 += __shfl_xor(a6, 16); a6 += __shfl_xor(a6, 32);
    a7 += __shfl_xor(a7, 8); a7 += __shfl_xor(a7, 16); a7 += __shfl_xor(a7, 32);
    if (h == 0) {
        float di = dinv[wid];
        float4 ba = ((const float4*)b)[2 * k];
        float4 bb = ((const float4*)b)[2 * k + 1];
        float o0 = fmaf(di, a0, ba.x);
        float o1 = fmaf(di, a1, ba.y);
        float o2 = fmaf(di, a2, ba.z);
        float o3 = fmaf(di, a3, ba.w);
        float o4 = fmaf(di, a4, bb.x);
        float o5 = fmaf(di, a5, bb.y);
        float o6 = fmaf(di, a6, bb.z);
        float o7 = fmaf(di, a7, bb.w);
        u32x4 pv;
        pv[0] = pack2(o0, o1); pv[1] = pack2(o2, o3);
        pv[2] = pack2(o4, o5); pv[3] = pack2(o6, o7);
        __builtin_nontemporal_store(pv, (u32x4*)(outbuf + (size_t)wid * 32) + k);
    }
}

// ---------------- decode: z is bf16 [N x 64] ----------------
__global__ void k_decode(const int* __restrict__ eli, const ushort16* __restrict__ z,
                         float* __restrict__ out) {
    int e = blockIdx.x * blockDim.x + threadIdx.x;
    if (e >= N_EL) return;
    int a = eli[e];
    int b = eli[N_EL + e];
    const uint4* za = (const uint4*)(z + (size_t)a * 64);
    const uint4* zb = (const uint4*)(z + (size_t)b * 64);
    float acc = 0.0f;
#pragma unroll
    for (int i = 0; i < 8; ++i) {
        uint4 va = za[i], vb = zb[i];
        acc += bf_lo(va.x) * bf_lo(vb.x) + bf_hi(va.x) * bf_hi(vb.x);
        acc += bf_lo(va.y) * bf_lo(vb.y) + bf_hi(va.y) * bf_hi(vb.y);
        acc += bf_lo(va.z) * bf_lo(vb.z) + bf_hi(va.z) * bf_hi(vb.z);
        acc += bf_lo(va.w) * bf_lo(vb.w) + bf_hi(va.w) * bf_hi(vb.w);
    }
    out[e] = acc;
}

extern "C" void kernel_launch(void* const* d_in, const int* in_sizes, int n_in,
                              void* d_out, int out_size, void* d_ws, size_t ws_size,
                              hipStream_t stream) {
    const float* x   = (const float*)d_in[0];
    const int*   ei  = (const int*)d_in[1];
    const int*   eli = (const int*)d_in[2];
    const float* W1  = (const float*)d_in[3];
    const float* b1  = (const float*)d_in[4];
    const float* W2  = (const float*)d_in[5];
    const float* b2  = (const float*)d_in[6];
    const float* W3  = (const float*)d_in[7];
    const float* b3  = (const float*)d_in[8];
    float* out = (float*)d_out;

    const int* srcA = ei;
    const int* dstA = ei + N_EDGES;

    // workspace layout (bytes):
    //   dinv [0, 400K)   lrp [1M, +400,004)
    //   bsum [1888K, +784)  boff [1896K, +784)
    //   col [2M, +6.4M)   r [9M, +6.4M)
    //   t   [16M, +25.6M+256)  bf16 N x 128 (+ zero pad row); layer-3 z dense
    //                          N x 64 in same buffer (z pad at N*128B)
    //   aggb [48M, +25.6M)  bf16 N x 128 (layers), N x 64 (final agg z)
    //   cpad [80M, +400K+64)  dense counters + scanF arrival counter
    char* ws = (char*)d_ws;
    float*    dinv   = (float*)   (ws + 0);
    int*      lrp    = (int*)     (ws + (1024u << 10));
    int*      bsum   = (int*)     (ws + (1888u << 10));
    int*      boff   = (int*)     (ws + (1896u << 10));
    int*      col    = (int*)     (ws + (2048u << 10));
    int*      r      = (int*)     (ws + (9u << 20));
    ushort16* t      = (ushort16*)(ws + (16u << 20));
    ushort16* aggb   = (ushort16*)(ws + (48u << 20));
    int*      cpad   = (int*)     (ws + (80u << 20));
    int*      cnt    = cpad + N_NODES;            // covered by memset

    const int B = 256;
    const int gG  = (N_NODES * 64 + B - 1) / B;   // 25000
    const int gEL = (N_EL + B - 1) / B;

    // ---- CSR build overlapped with GEMM1 (interleaved block roles) ----
    hipMemsetAsync(cpad, 0, ((size_t)N_NODES + 16) * sizeof(int), stream);
    k_fat1<<<GT_GEMM + GE_RANK, B, 0, stream>>>(x, W1, t, dstA, cpad, r);
    k_scanF<<<NB2, 512, 0, stream>>>(cpad, lrp, dinv, bsum, boff, cnt);
    k_fill2<<<GE_RANK, B, 0, stream>>>(srcA, dstA, lrp, boff, r, col);

    // ---- layer 1 aggregation (weighted: dinv[src] from LDS broadcast) ----
    k_gather128<true, true><<<gG, B, 0, stream>>>(lrp, boff, col, dinv,
                                                  (const uint32*)t, b1, (uint32*)aggb);
    // ---- layer 2 (epilogue prescales t by dinv) ----
    k_gemm_mfma<128, ushort16, true, 128, false><<<GT_GEMM, B, 0, stream>>>(
        aggb, W2, dinv, t);
    k_gather128<true, false><<<gG, B, 0, stream>>>(lrp, boff, col, dinv,
                                                   (const uint32*)t, b2, (uint32*)aggb);
    // ---- layer 3: dense 64-wide z (pad row zeroed by gemm3 block 0) ----
    k_gemm_mfma<64, ushort16, true, 64, true><<<GT_GEMM, B, 0, stream>>>(
        aggb, W3, dinv, t);
    k_gather64<<<gG, B, 0, stream>>>(lrp, boff, col, dinv, (const uint32*)t, b3,
                                     (uint32*)aggb);

    // ---- decode ----
    k_decode<<<gEL, B, 0, stream>>>(eli, aggb, out);
}